// Round 14
// baseline (37.741 us; speedup 1.0000x reference)
//
#include <hip/hip_runtime.h>

#define NCH   256
#define OUT_H 7
#define OUT_W 7
#define WPB   4      // independent waves per block
#define BPAD  68     // floats per band row (64 + pad)

// Wave = (roi, channel). Lane = absolute x-column (W=64 = wave width).
// Vertical band-max: ALL row loads issued into a static register array first
// (one latency exposure, ~42-deep MLP), then reduced; 7 band rows -> LDS;
// horizontal clamped reads. All ROI bounds scalar -> scalar guards.
__global__ __launch_bounds__(256) void roipool_kernel(
    const float* __restrict__ fm,   // (B, C, H, W)
    const int*   __restrict__ rois, // (N, 5): b, x1, y1, x2, y2
    float*       __restrict__ out)  // (N, C, 7, 7)
{
    __shared__ float bands[WPB][OUT_H][BPAD];   // 7616 B/block

    const int tid  = threadIdx.x;
    const int wv   = tid >> 6;
    const int lane = tid & 63;
    const int task = __builtin_amdgcn_readfirstlane(blockIdx.x * WPB + wv);
    const int n    = task >> 8;
    const int c    = task & 255;

    const int* r = rois + n * 5;    // scalar s_loads (task uniform)
    const int b  = r[0];
    const int x1 = r[1] >> 4;       // exact: x*(1/16.f) trunc, 0<=x<1024
    const int y1 = r[2] >> 4;
    const int x2 = r[3] >> 4;
    const int y2 = r[4] >> 4;
    const int h  = y2 - y1 + 1;     // 1..34
    const int w  = x2 - x1 + 1;     // 1..34, bins never empty

    // lane's fixed column address; only scalar row offsets vary per load
    const float* plane = fm + (((size_t)(b * NCH + c)) << 12) + lane;

    // scalar band geometry (magic /7 exact for x<=244: 9363*7=65541, slack ok)
    int hs[OUT_H], sp[OUT_H];
    #pragma unroll
    for (int i = 0; i < OUT_H; ++i) {
        hs[i] = y1 + ((i * h * 9363) >> 16);
        sp[i] = y1 + ((((i + 1) * h + 6) * 9363) >> 16) - hs[i];   // 1..6
    }

    // ---- issue ALL vertical loads (scalar-guarded), no reduction yet ----
    float v[OUT_H][6];                 // static indices only (no scratch)
    #pragma unroll
    for (int i = 0; i < OUT_H; ++i) {
        #pragma unroll
        for (int a = 0; a < 6; ++a) {
            if (a < sp[i])                         // SCALAR guard
                v[i][a] = plane[(hs[i] + a) << 6];
        }
    }
    __builtin_amdgcn_sched_barrier(0);  // keep all issues ahead of consumers

    // ---- reduce bands, write to LDS (64 distinct addrs, conflict-free) ----
    float* bw = &bands[wv][0][0];
    #pragma unroll
    for (int i = 0; i < OUT_H; ++i) {
        float m = v[i][0];
        #pragma unroll
        for (int a = 1; a < 6; ++a) {
            if (a < sp[i])                         // SCALAR guard
                m = fmaxf(m, v[i][a]);
        }
        bw[i * BPAD + lane] = m;
    }
    // same-wave LDS RAW: force completion + no reordering (rule-18 insurance)
    asm volatile("s_waitcnt lgkmcnt(0)" ::: "memory");
    __builtin_amdgcn_sched_barrier(0);

    // ---- horizontal: lanes 0..48 = cells; <=6 clamped reads ----
    if (lane < OUT_H * OUT_W) {
        const int i = (lane * 9363) >> 16;      // lane / 7
        const int j = lane - i * 7;
        const int ws  = (j * w * 9363) >> 16;                     // rel col
        const int we1 = ((((j + 1) * w + 6) * 9363) >> 16) - 1;   // last rel col

        // tight scalar bound on w-span: wq + T[rem], T={0,1,2,2,2,2,2}
        const int wq = (w * 9363) >> 16;
        const int wr = w - wq * 7;
        const int wbn = wq + (wr == 0 ? 0 : (wr == 1 ? 1 : 2));   // 1..6

        const float* br = &bands[wv][0][0] + i * BPAD + x1;
        float m = br[ws];
        #pragma unroll
        for (int bb = 1; bb < 6; ++bb) {
            if (bb < wbn) {                     // SCALAR guard
                const int cc = (ws + bb < we1) ? ws + bb : we1;   // lane clamp
                m = fmaxf(m, br[cc]);
            }
        }
        out[(size_t)task * (OUT_H * OUT_W) + lane] = m;  // 196 B contiguous
    }
}

extern "C" void kernel_launch(void* const* d_in, const int* in_sizes, int n_in,
                              void* d_out, int out_size, void* d_ws, size_t ws_size,
                              hipStream_t stream) {
    const float* fm   = (const float*)d_in[0];
    const int*   rois = (const int*)d_in[1];
    float*       out  = (float*)d_out;

    const int N = in_sizes[1] / 5;            // 256 rois
    dim3 grid((N * NCH) / WPB);               // 16384 blocks
    dim3 block(256);
    roipool_kernel<<<grid, block, 0, stream>>>(fm, rois, out);
}

// Round 15
// 33.499 us; speedup vs baseline: 1.1266x; 1.1266x over previous
//
#include <hip/hip_runtime.h>

#define NCH   256
#define OUT_H 7
#define OUT_W 7
#define WPB   4      // independent waves per block
#define BPAD  68     // floats per band row (64 + pad)

// Wave = (roi, channel). Lane = absolute x-column (W=64 = wave width).
// Vertical: 42 UNCONDITIONAL clamped row loads (straight-line, no branches
// -> nothing can sink), pinned above the reduce by a memory-clobber asm.
// Dup rows (beyond band span) are L1 hits and idempotent under max.
__global__ __launch_bounds__(256) void roipool_kernel(
    const float* __restrict__ fm,   // (B, C, H, W)
    const int*   __restrict__ rois, // (N, 5): b, x1, y1, x2, y2
    float*       __restrict__ out)  // (N, C, 7, 7)
{
    __shared__ float bands[WPB][OUT_H][BPAD];   // 7616 B/block

    const int tid  = threadIdx.x;
    const int wv   = tid >> 6;
    const int lane = tid & 63;
    const int task = __builtin_amdgcn_readfirstlane(blockIdx.x * WPB + wv);
    const int n    = task >> 8;
    const int c    = task & 255;

    const int* r = rois + n * 5;    // scalar s_loads (task uniform)
    const int b  = r[0];
    const int x1 = r[1] >> 4;       // exact: x*(1/16.f) trunc, 0<=x<1024
    const int y1 = r[2] >> 4;
    const int x2 = r[3] >> 4;
    const int y2 = r[4] >> 4;
    const int h  = y2 - y1 + 1;     // 1..34
    const int w  = x2 - x1 + 1;     // 1..34, bins never empty

    // lane's fixed column address; row offsets are scalar
    const float* plane = fm + (((size_t)(b * NCH + c)) << 12) + lane;

    // scalar band geometry + clamped row table (all SGPR math; magic /7
    // exact for args <= 244 here)
    int row[OUT_H][6];
    #pragma unroll
    for (int i = 0; i < OUT_H; ++i) {
        const int hs = y1 + ((i * h * 9363) >> 16);                  // first row
        const int le = y1 + ((((i + 1) * h + 6) * 9363) >> 16) - 1;  // last row
        #pragma unroll
        for (int a = 0; a < 6; ++a) {
            const int rr = hs + a;
            row[i][a] = (rr < le) ? rr : le;    // scalar clamp (dups benign)
        }
    }

    // ---- issue ALL 42 loads, branchless ----
    float v[OUT_H][6];
    #pragma unroll
    for (int i = 0; i < OUT_H; ++i) {
        #pragma unroll
        for (int a = 0; a < 6; ++a)
            v[i][a] = plane[row[i][a] << 6];
    }
    // memory-clobber: loads cannot sink below this point (IR or MIR)
    asm volatile("" ::: "memory");
    __builtin_amdgcn_sched_barrier(0);

    // ---- reduce bands (max3-friendly trees), write LDS conflict-free ----
    float* bw = &bands[wv][0][0];
    #pragma unroll
    for (int i = 0; i < OUT_H; ++i) {
        const float m01 = fmaxf(v[i][0], v[i][1]);
        const float m23 = fmaxf(v[i][2], v[i][3]);
        const float m45 = fmaxf(v[i][4], v[i][5]);
        bw[i * BPAD + lane] = fmaxf(fmaxf(m01, m23), m45);
    }
    // same-wave LDS RAW: force completion + no reordering
    asm volatile("s_waitcnt lgkmcnt(0)" ::: "memory");
    __builtin_amdgcn_sched_barrier(0);

    // ---- horizontal: lanes 0..48 = cells; 6 clamped reads, branchless ----
    if (lane < OUT_H * OUT_W) {
        const int i = (lane * 9363) >> 16;      // lane / 7
        const int j = lane - i * 7;
        const int ws  = (j * w * 9363) >> 16;                     // rel col
        const int we1 = ((((j + 1) * w + 6) * 9363) >> 16) - 1;   // last rel col

        const float* br = &bands[wv][0][0] + i * BPAD + x1;
        float m = br[ws];
        #pragma unroll
        for (int bb = 1; bb < 6; ++bb) {
            const int cc = (ws + bb < we1) ? ws + bb : we1;   // lane clamp
            m = fmaxf(m, br[cc]);
        }
        out[(size_t)task * (OUT_H * OUT_W) + lane] = m;  // 196 B contiguous
    }
}

extern "C" void kernel_launch(void* const* d_in, const int* in_sizes, int n_in,
                              void* d_out, int out_size, void* d_ws, size_t ws_size,
                              hipStream_t stream) {
    const float* fm   = (const float*)d_in[0];
    const int*   rois = (const int*)d_in[1];
    float*       out  = (float*)d_out;

    const int N = in_sizes[1] / 5;            // 256 rois
    dim3 grid((N * NCH) / WPB);               // 16384 blocks
    dim3 block(256);
    roipool_kernel<<<grid, block, 0, stream>>>(fm, rois, out);
}

// Round 16
// 32.427 us; speedup vs baseline: 1.1639x; 1.0330x over previous
//
#include <hip/hip_runtime.h>

#define NCH   256
#define FW    64
#define OUT_H 7
#define OUT_W 7
#define WPB   4      // independent waves per block
#define MAXH  34     // max region rows
#define LDSW  40     // floats per LDS row (10 quads)

// ---- Kernel A (tiny, once per launch): per-ROI descriptors + per-cell
// geometry into d_ws. Moves ~150 SALU/wave x 65536 waves of scalar work
// to 256 threads. Layout (ints): desc[n*8 + {0:qoff,1:passes,2:qn,3:hm1,4:hb}];
// celltab at 2048 + n*64 + cell: packed {hs, he1, ws_lds, wn} bytes.
__global__ __launch_bounds__(256) void prep_kernel(
    const int* __restrict__ rois, int* __restrict__ wsI, int nroi)
{
    const int n = blockIdx.x * blockDim.x + threadIdx.x;
    if (n >= nroi) return;
    const int b  = rois[n * 5 + 0];
    const int x1 = rois[n * 5 + 1] >> 4;   // exact: x*(1/16.f) trunc, x<1024
    const int y1 = rois[n * 5 + 2] >> 4;
    const int x2 = rois[n * 5 + 3] >> 4;
    const int y2 = rois[n * 5 + 4] >> 4;
    const int h = y2 - y1 + 1, w = x2 - x1 + 1;      // 1..34
    const int qs = x1 >> 2, qn = (x2 >> 2) - qs + 1, off = x1 & 3;
    const int hq = h / 7, hr = h - hq * 7;
    const int hb = hq + (hr == 0 ? 0 : (hr == 1 ? 1 : 2));   // wave-max h-span

    int* d = wsI + n * 8;
    d[0] = ((b * NCH) << 12) + (y1 << 6) + (qs << 2);  // staging elem offset
    d[1] = (h + 5) / 6;       // passes
    d[2] = qn;
    d[3] = h - 1;             // hm1 (staging row clamp)
    d[4] = hb;
    d[5] = 0; d[6] = 0; d[7] = 0;

    int* ct = wsI + 2048 + n * 64;
    for (int cell = 0; cell < 49; ++cell) {
        const int i = cell / 7, j = cell - i * 7;
        const int hs  = (i * h) / 7;                    // rel first row
        const int he1 = ((i + 1) * h + 6) / 7 - 1;      // rel last row
        const int wsr = (j * w) / 7;
        const int wn  = ((j + 1) * w + 6) / 7 - wsr;    // exact col span 1..6
        const int wsl = wsr + off;                      // LDS col of bin start
        ct[cell] = hs | (he1 << 8) | (wsl << 16) | (wn << 24);
    }
}

// ---- Kernel B: wave = (roi, channel). R9-proven staging; compute phase is
// SALU-free per element: per-lane packed geometry (1 coalesced load), imm-
// offset LDS reads, col masking via loop-invariant per-lane selects.
__global__ __launch_bounds__(256) void roipool_kernel(
    const float* __restrict__ fm,   // (B, C, H, W)
    const int*   __restrict__ wsI,  // descriptors + cell table
    float*       __restrict__ out)  // (N, C, 7, 7)
{
    // +8 pad: masked over-reads (rp[1..5] past a bin) stay in-bounds
    __shared__ __align__(16) float lds_all[WPB * MAXH * LDSW + 8];

    const int tid  = threadIdx.x;
    const int wv   = tid >> 6;
    const int lane = tid & 63;
    const int task = __builtin_amdgcn_readfirstlane(blockIdx.x * WPB + wv);
    const int n    = task >> 8;
    const int c    = task & 255;

    const int* dsc = wsI + n * 8;        // uniform -> s_load
    const int qoff   = dsc[0];
    const int passes = dsc[1];
    const int qn     = dsc[2];
    const int hm1    = dsc[3];
    const int hb     = dsc[4];

    // ---- stage: lane -> (row-group rr 0..5, quad qq 0..9), reg-batched ----
    const int rg = (lane * 6554) >> 16;  // lane/10
    const int rr = (rg == 6) ? 0 : rg;   // lanes 60..63 duplicate (benign)
    const int qq = lane - rg * 10;
    const float4* srcq = (const float4*)fm + (qoff >> 2) + (c << 10);
    const bool qok = (qq < qn);

    float4 v0, v1, v2, v3, v4, v5;
    int h0, h1, h2, h3, h4, h5;
    if (qok) {
        h0 = rr;
        v0 = srcq[h0 * (FW / 4) + qq];
        if (passes > 1) { h1 = rr + 6;  h1 = (h1 < hm1) ? h1 : hm1; v1 = srcq[h1 * (FW / 4) + qq]; }
        if (passes > 2) { h2 = rr + 12; h2 = (h2 < hm1) ? h2 : hm1; v2 = srcq[h2 * (FW / 4) + qq]; }
        if (passes > 3) { h3 = rr + 18; h3 = (h3 < hm1) ? h3 : hm1; v3 = srcq[h3 * (FW / 4) + qq]; }
        if (passes > 4) { h4 = rr + 24; h4 = (h4 < hm1) ? h4 : hm1; v4 = srcq[h4 * (FW / 4) + qq]; }
        if (passes > 5) { h5 = rr + 30; h5 = (h5 < hm1) ? h5 : hm1; v5 = srcq[h5 * (FW / 4) + qq]; }

        float4* ldsq = (float4*)(lds_all + wv * (MAXH * LDSW));
        ldsq[h0 * (LDSW / 4) + qq] = v0;
        if (passes > 1) ldsq[h1 * (LDSW / 4) + qq] = v1;
        if (passes > 2) ldsq[h2 * (LDSW / 4) + qq] = v2;
        if (passes > 3) ldsq[h3 * (LDSW / 4) + qq] = v3;
        if (passes > 4) ldsq[h4 * (LDSW / 4) + qq] = v4;
        if (passes > 5) ldsq[h5 * (LDSW / 4) + qq] = v5;
    }
    // no barrier: same wave produces and consumes (lgkmcnt orders)

    // ---- compute: lane = cell; geometry from table, masked imm-offset reads ----
    if (lane < OUT_H * OUT_W) {
        const int cd  = (wsI + 2048 + n * 64)[lane];   // 196 B coalesced
        const int hs  = cd & 0xff;
        const int he1 = (cd >> 8) & 0xff;
        const int wsl = (cd >> 16) & 0xff;
        const int wn  = cd >> 24;

        const float* tb = lds_all + wv * (MAXH * LDSW);
        float m = -INFINITY;
        #pragma unroll
        for (int a = 0; a < 6; ++a) {
            if (a < hb) {                                // SCALAR guard only
                const int hh = (hs + a < he1) ? hs + a : he1;   // lane clamp
                const float* rp = tb + hh * LDSW + wsl;
                const float r0 = rp[0], r1 = rp[1], r2 = rp[2]; // imm offsets
                const float r3 = rp[3], r4 = rp[4], r5 = rp[5];
                m = fmaxf(m, r0);                               // wn >= 1
                m = fmaxf(m, (1 < wn) ? r1 : -INFINITY);        // VALU masks
                m = fmaxf(m, (2 < wn) ? r2 : -INFINITY);
                m = fmaxf(m, (3 < wn) ? r3 : -INFINITY);
                m = fmaxf(m, (4 < wn) ? r4 : -INFINITY);
                m = fmaxf(m, (5 < wn) ? r5 : -INFINITY);
            }
        }
        out[(size_t)task * (OUT_H * OUT_W) + lane] = m;  // 196 B contiguous
    }
}

extern "C" void kernel_launch(void* const* d_in, const int* in_sizes, int n_in,
                              void* d_out, int out_size, void* d_ws, size_t ws_size,
                              hipStream_t stream) {
    const float* fm   = (const float*)d_in[0];
    const int*   rois = (const int*)d_in[1];
    float*       out  = (float*)d_out;
    int*         wsI  = (int*)d_ws;

    const int N = in_sizes[1] / 5;            // 256 rois
    prep_kernel<<<dim3((N + 255) / 256), 256, 0, stream>>>(rois, wsI, N);

    dim3 grid((N * NCH) / WPB);               // 16384 blocks
    roipool_kernel<<<grid, dim3(256), 0, stream>>>(fm, wsI, out);
}

// Round 17
// 26.301 us; speedup vs baseline: 1.4350x; 1.2329x over previous
//
#include <hip/hip_runtime.h>

#define NCH   256
#define FW    64
#define OUT_H 7
#define OUT_W 7
#define WPB   4      // independent waves per block
#define MAXH  34     // max region rows
#define LDSW  40     // floats per LDS row (10 quads)

// R9 structure (4x validated) + XCD channel-slab swizzle: XCD k (= bid%8,
// round-robin dispatch heuristic) processes only channels [32k, 32k+32) ->
// per-XCD fm footprint 2MB (L2-resident) instead of 16MB (4x thrash).
__global__ __launch_bounds__(256) void roipool_kernel(
    const float* __restrict__ fm,   // (B, C, H, W)
    const int*   __restrict__ rois, // (N, 5): b, x1, y1, x2, y2
    float*       __restrict__ out)  // (N, C, 7, 7)
{
    __shared__ __align__(16) float lds[WPB][MAXH][LDSW];  // 21760 B

    const int tid  = threadIdx.x;
    const int wv   = tid >> 6;
    const int lane = tid & 63;

    // swizzle: bid -> (slab=XCD, n, channel-quad); block's 4 waves = 4
    // consecutive channels inside one slab. Coverage is a bijection.
    const int bid  = blockIdx.x;
    const int slab = bid & 7;            // target XCD (bid % 8 round-robin)
    const int s    = bid >> 3;           // 0..2047 within slab
    const int nn   = s >> 3;             // roi index
    const int q    = s & 7;              // channel-quad within slab
    const int task = __builtin_amdgcn_readfirstlane(
        (nn << 8) + (slab << 5) + (q << 2) + wv);
    const int n    = task >> 8;
    const int c    = task & 255;

    const int* r = rois + n * 5;    // scalar loads (task uniform)
    const int b  = r[0];
    const int x1 = r[1] >> 4;       // exact: x*(1/16.f) trunc, 0<=x<1024
    const int y1 = r[2] >> 4;
    const int x2 = r[3] >> 4;
    const int y2 = r[4] >> 4;
    const int h_roi = y2 - y1 + 1;  // 1..34
    const int w_roi = x2 - x1 + 1;  // 1..34, bins never empty
    const int qs  = x1 >> 2;        // first aligned quad of region rows
    const int qn  = (x2 >> 2) - qs + 1;   // quads per row, 1..10
    const int off = x1 & 3;         // LDS col of x1

    // Tight SCALAR band-span bounds: max span = q + T[r], T={0,1,2,2,2,2,2}
    const int hq = h_roi / 7, hr = h_roi - hq * 7;
    const int wq = w_roi / 7, wr = w_roi - wq * 7;
    const int hb  = hq + (hr == 0 ? 0 : (hr == 1 ? 1 : 2));   // 1..6
    const int wbn = wq + (wr == 0 ? 0 : (wr == 1 ? 1 : 2));   // 1..6

    // ---- stage: lane -> (row-group rr 0..5, quad qq 0..9), reg-batched ----
    const int rg = lane / 10;            // 0..6
    const int rr = (rg == 6) ? 0 : rg;   // lanes 60..63 duplicate (benign)
    const int qq = lane - rg * 10;       // 0..9 (0..3 for lanes 60..63)
    const int passes = (h_roi + 5) / 6;  // scalar, 1..6

    const float4* srcq =
        (const float4*)(fm + (((size_t)(b * NCH + c)) << 12) + ((size_t)y1 << 6)) + qs;
    const bool qok = (qq < qn);

    float4 v0, v1, v2, v3, v4, v5;       // staged quads (conditionally live)
    int h0, h1, h2, h3, h4, h5;
    if (qok) {
        // clamped row index per pass; dup loads/writes benign (same data)
        h0 = rr;                                   // p=0 always
        v0 = srcq[h0 * (FW / 4) + qq];
        if (passes > 1) { h1 = rr + 6;  h1 = (h1 < h_roi) ? h1 : (h_roi - 1); v1 = srcq[h1 * (FW / 4) + qq]; }
        if (passes > 2) { h2 = rr + 12; h2 = (h2 < h_roi) ? h2 : (h_roi - 1); v2 = srcq[h2 * (FW / 4) + qq]; }
        if (passes > 3) { h3 = rr + 18; h3 = (h3 < h_roi) ? h3 : (h_roi - 1); v3 = srcq[h3 * (FW / 4) + qq]; }
        if (passes > 4) { h4 = rr + 24; h4 = (h4 < h_roi) ? h4 : (h_roi - 1); v4 = srcq[h4 * (FW / 4) + qq]; }
        if (passes > 5) { h5 = rr + 30; h5 = (h5 < h_roi) ? h5 : (h_roi - 1); v5 = srcq[h5 * (FW / 4) + qq]; }

        float4* ldsq = (float4*)&lds[wv][0][0];
        ldsq[h0 * (LDSW / 4) + qq] = v0;
        if (passes > 1) ldsq[h1 * (LDSW / 4) + qq] = v1;
        if (passes > 2) ldsq[h2 * (LDSW / 4) + qq] = v2;
        if (passes > 3) ldsq[h3 * (LDSW / 4) + qq] = v3;
        if (passes > 4) ldsq[h4 * (LDSW / 4) + qq] = v4;
        if (passes > 5) ldsq[h5 * (LDSW / 4) + qq] = v5;
    }
    // no barrier: same wave produces and consumes its LDS slice (lgkmcnt orders)

    // ---- compute: lane = cell; scalar-trip clamped reads (avg ~4x4, max 6x6) ----
    if (lane < OUT_H * OUT_W) {
        const int i = lane / OUT_W;
        const int j = lane - i * OUT_W;

        const int hs  = (i * h_roi) / OUT_H;
        const int he1 = ((i + 1) * h_roi + 6) / OUT_H - 1;        // last row
        const int ws  = (j * w_roi) / OUT_W + off;
        const int we1 = ((j + 1) * w_roi + 6) / OUT_W - 1 + off;  // last col

        int cb[6];                      // clamped cols, compile-time indexed
        #pragma unroll
        for (int bb = 0; bb < 6; ++bb) {
            const int w = ws + bb;
            cb[bb] = (w < we1) ? w : we1;
        }

        const float* tb = &lds[wv][0][0];
        float m = -INFINITY;
        #pragma unroll
        for (int a = 0; a < 6; ++a) {
            if (a < hb) {                            // SCALAR guard (sgpr hb)
                const int hh = (hs + a < he1) ? hs + a : he1;   // lane clamp
                const float* rp = tb + hh * LDSW;
                #pragma unroll
                for (int bb = 0; bb < 6; ++bb) {
                    if (bb < wbn)                    // SCALAR guard (sgpr wbn)
                        m = fmaxf(m, rp[cb[bb]]);
                }
            }
        }
        out[(size_t)task * (OUT_H * OUT_W) + lane] = m;  // 196 B contiguous/wave
    }
}

extern "C" void kernel_launch(void* const* d_in, const int* in_sizes, int n_in,
                              void* d_out, int out_size, void* d_ws, size_t ws_size,
                              hipStream_t stream) {
    const float* fm   = (const float*)d_in[0];
    const int*   rois = (const int*)d_in[1];
    float*       out  = (float*)d_out;

    const int N = in_sizes[1] / 5;            // 256 rois
    dim3 grid((N * NCH) / WPB);               // 16384 blocks
    dim3 block(256);
    roipool_kernel<<<grid, block, 0, stream>>>(fm, rois, out);
}